// Round 18
// baseline (56.537 us; speedup 1.0000x reference)
//
#include <hip/hip_runtime.h>
#include <math.h>

#define MOMN 76   // power sums S_0..S_75 (wave-split scan covers n <= 75)
#define NCO  72   // series coefficients n=0..71 (tail < 1e-13 for |qf| <= ~20)

// Moment-method d=1 attention: e^{qf} = sum_n (qf)^n/n!.  Per batch: power sums
// S'_n = sum (f/4)^n in f32, coefficients + Horner in f64 with x = 4q.
// Fused-attn moments via additivity: S_n(fused) = S_n(sent)+S_n(ctx0)+S_n(ctx1).
// ws: ctx[32*1536] | mom[32][3][76] | final[32*3840] | hpart[32*8*256]
// 4 dispatches: k1 (attns + proj0 + all component moments), k2 (9 trivial fused
// slices + proj1/2), mlp_b (batch-tiled stage 1), mlp_tail.

__device__ __forceinline__ float red64f(float x) {
    x += __shfl_xor(x, 1, 64);
    x += __shfl_xor(x, 2, 64);
    x += __shfl_xor(x, 4, 64);
    x += __shfl_xor(x, 8, 64);
    x += __shfl_xor(x, 16, 64);
    x += __shfl_xor(x, 32, 64);
    return x;
}

// Sync-free wave-split power-sum scan of a 768-vector (256 thr = 4 waves).
// Wave w computes S_n for n = w + 4i, i = 0..18 (covers n <= 75). Caller syncs.
__device__ __forceinline__ void scan768_S(const float* __restrict__ x,
                                          float* __restrict__ partS, int tid) {
    const int w = tid >> 6, lane = tid & 63;
    float pw[12], g4[12];
    #pragma unroll
    for (int e = 0; e < 12; ++e) {
        const float g  = x[lane + 64 * e] * 0.25f;
        const float g2 = g * g;
        g4[e] = g2 * g2;
        pw[e] = (w == 0) ? 1.f : ((w == 1) ? g : ((w == 2) ? g2 : g2 * g));
    }
    for (int i = 0; i < 19; ++i) {
        float s = ((pw[0] + pw[1]) + (pw[2] + pw[3]))
                + ((pw[4] + pw[5]) + (pw[6] + pw[7]))
                + ((pw[8] + pw[9]) + (pw[10] + pw[11]));
        s = red64f(s);
        if (lane == 0) partS[w + 4 * i] = s;
        #pragma unroll
        for (int e = 0; e < 12; ++e) pw[e] *= g4[e];
    }
}

// Same plus T_n = sum g^n * v (v unscaled).
__device__ __forceinline__ void scan768_ST(const float* __restrict__ x,
                                           const float* __restrict__ v,
                                           float* __restrict__ partS,
                                           float* __restrict__ partT, int tid) {
    const int w = tid >> 6, lane = tid & 63;
    float pw[12], g4[12], vv[12];
    #pragma unroll
    for (int e = 0; e < 12; ++e) {
        const float g  = x[lane + 64 * e] * 0.25f;
        const float g2 = g * g;
        g4[e] = g2 * g2;
        pw[e] = (w == 0) ? 1.f : ((w == 1) ? g : ((w == 2) ? g2 : g2 * g));
        vv[e] = v[lane + 64 * e];
    }
    for (int i = 0; i < 19; ++i) {
        float s = ((pw[0] + pw[1]) + (pw[2] + pw[3]))
                + ((pw[4] + pw[5]) + (pw[6] + pw[7]))
                + ((pw[8] + pw[9]) + (pw[10] + pw[11]));
        float t = ((pw[0]*vv[0] + pw[1]*vv[1]) + (pw[2]*vv[2] + pw[3]*vv[3]))
                + ((pw[4]*vv[4] + pw[5]*vv[5]) + (pw[6]*vv[6] + pw[7]*vv[7]))
                + ((pw[8]*vv[8] + pw[9]*vv[9]) + (pw[10]*vv[10] + pw[11]*vv[11]));
        s = red64f(s);
        t = red64f(t);
        if (lane == 0) { partS[w + 4 * i] = s; partT[w + 4 * i] = t; }
        #pragma unroll
        for (int e = 0; e < 12; ++e) pw[e] *= g4[e];
    }
}

// K1: grid (32,3), 256 threads.
//  y=0: scene ctx  (scan ST + eval 768 rows + rescan ctx -> mom[1])
//  y=1: speaker ctx (scan S + eval 768 rows q=other + rescan ctx -> mom[2])
//  y=2: sentence moments (scan S -> mom[0]) + sentence projection
__global__ __launch_bounds__(256) void k1_small_kernel(
    const float* __restrict__ sentence,
    const float* __restrict__ target,
    const float* __restrict__ other,
    const float* __restrict__ scene_desc,
    const float* __restrict__ scene_sent,
    const float* __restrict__ Ws,
    const float* __restrict__ bs,
    float* __restrict__ ctx,
    float* __restrict__ mom,
    float* __restrict__ final_)
{
    const int b = blockIdx.x, y = blockIdx.y, tid = threadIdx.x;
    __shared__ float xb[768];
    __shared__ float vbuf[768];
    __shared__ float partS[MOMN];
    __shared__ float partT[MOMN];
    __shared__ double coefA[NCO];
    __shared__ double coefB[NCO];
    __shared__ float redf[1024];

    if (y == 2) {
        for (int i = tid; i < 768; i += 256) xb[i] = sentence[b * 768 + i];
        __syncthreads();
        scan768_S(xb, partS, tid);          // sync-free; partS committed at next barrier

        const int g = tid >> 7;             // 0..1
        const int q = tid & 127;
        const float4* __restrict__ Wv = (const float4*)Ws;   // [768][128]
        float ax = 0.f, ay = 0.f, az = 0.f, aw = 0.f;
        #pragma unroll 8
        for (int k = g; k < 768; k += 2) {
            const float xv = xb[k];
            const float4 w = Wv[k * 128 + q];
            ax += xv * w.x; ay += xv * w.y; az += xv * w.z; aw += xv * w.w;
        }
        redf[g * 512 + q * 4 + 0] = ax;
        redf[g * 512 + q * 4 + 1] = ay;
        redf[g * 512 + q * 4 + 2] = az;
        redf[g * 512 + q * 4 + 3] = aw;
        __syncthreads();

        float* dst = final_ + b * 3840 + 2304;
        dst[tid]       = bs[tid]       + redf[tid]       + redf[512 + tid];
        dst[tid + 256] = bs[tid + 256] + redf[tid + 256] + redf[512 + tid + 256];
        if (tid < MOMN) mom[(b * 3 + 0) * MOMN + tid] = partS[tid];
        return;
    }

    const bool scene = (y == 0);
    const float* kp = scene ? (scene_sent + b * 768) : (target + b * 768);
    for (int i = tid; i < 768; i += 256) xb[i] = kp[i];
    if (scene)
        for (int i = tid; i < 768; i += 256) vbuf[i] = scene_desc[b * 768 + i];
    __syncthreads();
    if (scene) scan768_ST(xb, vbuf, partS, partT, tid);
    else       scan768_S(xb, partS, tid);
    __syncthreads();

    if (tid < NCO) {
        double fact = 1.0;
        for (int i = 2; i <= tid; ++i) fact *= (double)i;
        const double inv = 1.0 / fact;
        coefA[tid] = (double)partS[tid] * inv;
        coefB[tid] = scene ? ((double)partT[tid] * inv)
                           : ((double)partS[tid + 1] * inv);
    }
    __syncthreads();

    double q[3], num[3], den[3];
    #pragma unroll
    for (int j = 0; j < 3; ++j) {
        const int r = tid + 256 * j;
        q[j] = 4.0 * (double)(scene ? xb[r] : other[b * 768 + r]);
        den[j] = coefA[NCO - 1];
        num[j] = coefB[NCO - 1];
    }
    for (int n = NCO - 2; n >= 0; --n) {
        const double a = coefA[n], cc = coefB[n];
        #pragma unroll
        for (int j = 0; j < 3; ++j) {
            den[j] = fma(den[j], q[j], a);
            num[j] = fma(num[j], q[j], cc);
        }
    }
    #pragma unroll
    for (int j = 0; j < 3; ++j) {
        const float cv = (float)(scene ? (num[j] / den[j]) : (4.0 * num[j] / den[j]));
        ctx[b * 1536 + (scene ? 0 : 768) + tid + 256 * j] = cv;
        vbuf[tid + 256 * j] = cv;           // ctx slice for rescan
    }
    __syncthreads();
    scan768_S(vbuf, partS, tid);
    __syncthreads();
    if (tid < MOMN) mom[(b * 3 + (scene ? 1 : 2)) * MOMN + tid] = partS[tid];
}

// K2: grid (32,11), 256 threads.
//  y=0..8: fused slice via moment additivity (no scan, no staging)
//  y=9,10: ctx projections
__global__ __launch_bounds__(256) void k2_fused_kernel(
    const float* __restrict__ sentence,
    const float* __restrict__ ctx,
    const float* __restrict__ Ws,
    const float* __restrict__ bs,
    const float* __restrict__ mom,
    float* __restrict__ final_)
{
    const int b = blockIdx.x, y = blockIdx.y, tid = threadIdx.x;
    __shared__ float partS[MOMN];
    __shared__ double coefA[NCO];
    __shared__ double coefB[NCO];
    __shared__ float xb[768];
    __shared__ float redf[1024];

    if (y >= 9) {
        const int p = y - 8;     // 1 or 2
        const float* xsrc = ctx + b * 1536 + (p - 1) * 768;
        for (int i = tid; i < 768; i += 256) xb[i] = xsrc[i];
        __syncthreads();
        const int g = tid >> 7;
        const int q = tid & 127;
        const float4* __restrict__ Wv = (const float4*)Ws;
        float ax = 0.f, ay = 0.f, az = 0.f, aw = 0.f;
        #pragma unroll 8
        for (int k = g; k < 768; k += 2) {
            const float xv = xb[k];
            const float4 w = Wv[k * 128 + q];
            ax += xv * w.x; ay += xv * w.y; az += xv * w.z; aw += xv * w.w;
        }
        redf[g * 512 + q * 4 + 0] = ax;
        redf[g * 512 + q * 4 + 1] = ay;
        redf[g * 512 + q * 4 + 2] = az;
        redf[g * 512 + q * 4 + 3] = aw;
        __syncthreads();
        float* dst = final_ + b * 3840 + 2304 + p * 512;
        dst[tid]       = bs[tid]       + redf[tid]       + redf[512 + tid];
        dst[tid + 256] = bs[tid + 256] + redf[tid + 256] + redf[512 + tid + 256];
        return;
    }

    if (tid < MOMN)
        partS[tid] = mom[(b * 3 + 0) * MOMN + tid]
                   + mom[(b * 3 + 1) * MOMN + tid]
                   + mom[(b * 3 + 2) * MOMN + tid];
    __syncthreads();
    if (tid < NCO) {
        double fact = 1.0;
        for (int i = 2; i <= tid; ++i) fact *= (double)i;
        const double inv = 1.0 / fact;
        coefA[tid] = (double)partS[tid] * inv;
        coefB[tid] = (double)partS[tid + 1] * inv;
    }
    __syncthreads();

    const int r = y * 256 + tid;
    const float fq = (r < 768) ? sentence[b * 768 + r] : ctx[b * 1536 + (r - 768)];
    const double x = 4.0 * (double)fq;
    double den = coefA[NCO - 1], num = coefB[NCO - 1];
    for (int n = NCO - 2; n >= 0; --n) {
        den = fma(den, x, coefA[n]);
        num = fma(num, x, coefB[n]);
    }
    final_[b * 3840 + r] = (float)(4.0 * num / den);
}

// MLP stage 1, batch-tiled: grid (8 b-groups, 8 k-chunks), 1024 threads.
// Block (bg, c): batches [4bg,4bg+4), K rows [480c,480c+480), all 256 cols.
// W1 slice read once per 4 batches (L2 traffic 126 -> 31 MB).
__global__ __launch_bounds__(1024) void mlp_b_kernel(
    const float* __restrict__ final_,
    const float* __restrict__ W1,   // [3840, 256]
    float* __restrict__ hpart)      // [32][8][256]
{
    const int bg = blockIdx.x;      // batch group: batches 4bg..4bg+3
    const int c  = blockIdx.y;      // k chunk
    const int tid = threadIdx.x;
    const int base = c * 480;

    __shared__ float act[4][480];   // [bb][k], rows 1920 B (16B-aligned)
    __shared__ float red[16][256];  // [kg*4+bb][col]

    for (int i = tid; i < 4 * 480; i += 1024) {
        const int bb = i / 480, k = i - bb * 480;
        act[bb][k] = final_[(4 * bg + bb) * 3840 + base + k];
    }
    __syncthreads();

    const int col = tid & 255;      // 0..255
    const int kg  = tid >> 8;       // 0..3, k window [120kg, 120kg+120)
    const float4* __restrict__ a0 = (const float4*)act[0];
    const float4* __restrict__ a1 = (const float4*)act[1];
    const float4* __restrict__ a2 = (const float4*)act[2];
    const float4* __restrict__ a3 = (const float4*)act[3];
    float acc0 = 0.f, acc1 = 0.f, acc2 = 0.f, acc3 = 0.f;
    const int k0 = kg * 120;
    #pragma unroll 2
    for (int j = 0; j < 120; j += 4) {
        const int k = k0 + j;
        const float4 v0 = a0[k >> 2];
        const float4 v1 = a1[k >> 2];
        const float4 v2 = a2[k >> 2];
        const float4 v3 = a3[k >> 2];
        const float w0 = W1[(base + k + 0) * 256 + col];
        const float w1 = W1[(base + k + 1) * 256 + col];
        const float w2 = W1[(base + k + 2) * 256 + col];
        const float w3 = W1[(base + k + 3) * 256 + col];
        acc0 = fmaf(v0.x, w0, acc0); acc0 = fmaf(v0.y, w1, acc0);
        acc0 = fmaf(v0.z, w2, acc0); acc0 = fmaf(v0.w, w3, acc0);
        acc1 = fmaf(v1.x, w0, acc1); acc1 = fmaf(v1.y, w1, acc1);
        acc1 = fmaf(v1.z, w2, acc1); acc1 = fmaf(v1.w, w3, acc1);
        acc2 = fmaf(v2.x, w0, acc2); acc2 = fmaf(v2.y, w1, acc2);
        acc2 = fmaf(v2.z, w2, acc2); acc2 = fmaf(v2.w, w3, acc2);
        acc3 = fmaf(v3.x, w0, acc3); acc3 = fmaf(v3.y, w1, acc3);
        acc3 = fmaf(v3.z, w2, acc3); acc3 = fmaf(v3.w, w3, acc3);
    }
    red[kg * 4 + 0][col] = acc0;
    red[kg * 4 + 1][col] = acc1;
    red[kg * 4 + 2][col] = acc2;
    red[kg * 4 + 3][col] = acc3;
    __syncthreads();

    // 1024 outputs: (bb, col) summed over 4 kg
    const int bb = tid >> 8;
    float s = red[0 * 4 + bb][col] + red[1 * 4 + bb][col]
            + red[2 * 4 + bb][col] + red[3 * 4 + bb][col];
    hpart[((4 * bg + bb) * 8 + c) * 256 + col] = s;
}

// MLP tail: combine K-partials, relu, [256x7] head, sigmoid. grid 32, 512 threads.
__global__ __launch_bounds__(512) void mlp_tail_kernel(
    const float* __restrict__ hpart,
    const float* __restrict__ b1,
    const float* __restrict__ W2,   // [256, 7]
    const float* __restrict__ b2,
    float* __restrict__ out)        // [32, 7]
{
    const int b = blockIdx.x;
    const int tid = threadIdx.x;

    __shared__ float hb[256];
    if (tid < 256) {
        float s = b1[tid];
        #pragma unroll
        for (int c = 0; c < 8; ++c) s += hpart[(b * 8 + c) * 256 + tid];
        hb[tid] = fmaxf(s, 0.f);
    }
    __syncthreads();

    const int w = tid >> 6;
    const int lane = tid & 63;
    if (w < 7) {
        float a = 0.f;
        #pragma unroll
        for (int c = lane; c < 256; c += 64)
            a += hb[c] * W2[c * 7 + w];
        #pragma unroll
        for (int off = 32; off > 0; off >>= 1)
            a += __shfl_down(a, off, 64);
        if (lane == 0)
            out[b * 7 + w] = 1.f / (1.f + __expf(-(a + b2[w])));
    }
}

extern "C" void kernel_launch(void* const* d_in, const int* in_sizes, int n_in,
                              void* d_out, int out_size, void* d_ws, size_t ws_size,
                              hipStream_t stream) {
    const float* sentence   = (const float*)d_in[0];
    const float* target     = (const float*)d_in[1];
    const float* other      = (const float*)d_in[2];
    const float* scene_desc = (const float*)d_in[3];
    const float* scene_sent = (const float*)d_in[4];
    const float* Ws         = (const float*)d_in[5];
    const float* bs         = (const float*)d_in[6];
    const float* W1         = (const float*)d_in[7];
    const float* b1         = (const float*)d_in[8];
    const float* W2         = (const float*)d_in[9];
    const float* b2         = (const float*)d_in[10];
    float* out = (float*)d_out;

    float* ctx    = (float*)d_ws;             // 32*1536
    float* mom    = ctx + 32 * 1536;          // 32*3*76
    float* final_ = mom + 32 * 3 * MOMN;      // 32*3840
    float* hpart  = final_ + 32 * 3840;       // 32*8*256

    k1_small_kernel<<<dim3(32, 3), 256, 0, stream>>>(sentence, target, other,
                                                     scene_desc, scene_sent,
                                                     Ws, bs, ctx, mom, final_);
    k2_fused_kernel<<<dim3(32, 11), 256, 0, stream>>>(sentence, ctx, Ws, bs, mom, final_);
    mlp_b_kernel<<<dim3(8, 8), 1024, 0, stream>>>(final_, W1, hpart);
    mlp_tail_kernel<<<32, 512, 0, stream>>>(hpart, b1, W2, b2, out);
}

// Round 19
// 50.463 us; speedup vs baseline: 1.1203x; 1.1203x over previous
//
#include <hip/hip_runtime.h>
#include <math.h>

#define NPOW 80   // power sums computed (n = 0..79 in k2; 0..75 in k1 scan)
#define NCO  72   // series coefficients n=0..71 (tail < 1e-13 for |qf| <= ~20)

// Moment-method d=1 attention: e^{qf} = sum_n (qf)^n/n!.  Per batch: power sums
// S'_n = sum (f/4)^n in f32 (no overflow), coefficients + Horner in f64, x = 4q.
// ws: ctx[32*1536] | final[32*3840] | hpart[32*8*256]
// 4 dispatches (r13 structure): k1 (2 attn blocks + proj0), k2 (9 fused + proj1/2),
// mlp_part, mlp_tail.  No atomics, no fences.

__device__ __forceinline__ float red64f(float x) {
    x += __shfl_xor(x, 1, 64);
    x += __shfl_xor(x, 2, 64);
    x += __shfl_xor(x, 4, 64);
    x += __shfl_xor(x, 8, 64);
    x += __shfl_xor(x, 16, 64);
    x += __shfl_xor(x, 32, 64);
    return x;
}

// Sync-free wave-split power-sum scan of a 768-vector (256 thr = 4 waves).
// Wave w computes S_n for n = w + 4i, i = 0..18 (covers n <= 75). Caller syncs.
__device__ __forceinline__ void scan768_S(const float* __restrict__ x,
                                          float* __restrict__ partS, int tid) {
    const int w = tid >> 6, lane = tid & 63;
    float pw[12], g4[12];
    #pragma unroll
    for (int e = 0; e < 12; ++e) {
        const float g  = x[lane + 64 * e] * 0.25f;
        const float g2 = g * g;
        g4[e] = g2 * g2;
        pw[e] = (w == 0) ? 1.f : ((w == 1) ? g : ((w == 2) ? g2 : g2 * g));
    }
    for (int i = 0; i < 19; ++i) {
        float s = ((pw[0] + pw[1]) + (pw[2] + pw[3]))
                + ((pw[4] + pw[5]) + (pw[6] + pw[7]))
                + ((pw[8] + pw[9]) + (pw[10] + pw[11]));
        s = red64f(s);
        if (lane == 0) partS[w + 4 * i] = s;
        #pragma unroll
        for (int e = 0; e < 12; ++e) pw[e] *= g4[e];
    }
}

// Same plus T_n = sum g^n * v (v unscaled).
__device__ __forceinline__ void scan768_ST(const float* __restrict__ x,
                                           const float* __restrict__ v,
                                           float* __restrict__ partS,
                                           float* __restrict__ partT, int tid) {
    const int w = tid >> 6, lane = tid & 63;
    float pw[12], g4[12], vv[12];
    #pragma unroll
    for (int e = 0; e < 12; ++e) {
        const float g  = x[lane + 64 * e] * 0.25f;
        const float g2 = g * g;
        g4[e] = g2 * g2;
        pw[e] = (w == 0) ? 1.f : ((w == 1) ? g : ((w == 2) ? g2 : g2 * g));
        vv[e] = v[lane + 64 * e];
    }
    for (int i = 0; i < 19; ++i) {
        float s = ((pw[0] + pw[1]) + (pw[2] + pw[3]))
                + ((pw[4] + pw[5]) + (pw[6] + pw[7]))
                + ((pw[8] + pw[9]) + (pw[10] + pw[11]));
        float t = ((pw[0]*vv[0] + pw[1]*vv[1]) + (pw[2]*vv[2] + pw[3]*vv[3]))
                + ((pw[4]*vv[4] + pw[5]*vv[5]) + (pw[6]*vv[6] + pw[7]*vv[7]))
                + ((pw[8]*vv[8] + pw[9]*vv[9]) + (pw[10]*vv[10] + pw[11]*vv[11]));
        s = red64f(s);
        t = red64f(t);
        if (lane == 0) { partS[w + 4 * i] = s; partT[w + 4 * i] = t; }
        #pragma unroll
        for (int e = 0; e < 12; ++e) pw[e] *= g4[e];
    }
}

// ---- projection helper: [768] x [768,512] with 256 threads, 2-way K-split
__device__ __forceinline__ void proj_256(
    const float* __restrict__ xsrc,
    const float* __restrict__ Ws,            // [768, 512]
    const float* __restrict__ bs,            // [512]
    float* __restrict__ dst,
    float* xb,                               // LDS [768]
    float* redf,                             // LDS [1024]
    int tid)
{
    for (int i = tid; i < 768; i += 256) xb[i] = xsrc[i];
    __syncthreads();

    const int g = tid >> 7;        // 0..1
    const int q = tid & 127;       // column quad
    const float4* __restrict__ Wv = (const float4*)Ws;   // [768][128]
    float ax = 0.f, ay = 0.f, az = 0.f, aw = 0.f;
    #pragma unroll 8
    for (int k = g; k < 768; k += 2) {
        const float xv = xb[k];
        const float4 w = Wv[k * 128 + q];
        ax += xv * w.x; ay += xv * w.y; az += xv * w.z; aw += xv * w.w;
    }
    redf[g * 512 + q * 4 + 0] = ax;
    redf[g * 512 + q * 4 + 1] = ay;
    redf[g * 512 + q * 4 + 2] = az;
    redf[g * 512 + q * 4 + 3] = aw;
    __syncthreads();

    dst[tid]       = bs[tid]       + redf[tid]       + redf[512 + tid];
    dst[tid + 256] = bs[tid + 256] + redf[tid + 256] + redf[512 + tid + 256];
}

// K1: grid (32,3), 256 threads.
//  y=0: scene ctx  (sync-free scan ST + eval all 768 rows, 3/thread)
//  y=1: speaker ctx (sync-free scan S + eval 768 rows with q=other)
//  y=2: sentence projection
__global__ __launch_bounds__(256) void k1_small_kernel(
    const float* __restrict__ sentence,
    const float* __restrict__ target,
    const float* __restrict__ other,
    const float* __restrict__ scene_desc,
    const float* __restrict__ scene_sent,
    const float* __restrict__ Ws,
    const float* __restrict__ bs,
    float* __restrict__ ctx,
    float* __restrict__ final_)
{
    const int b = blockIdx.x, y = blockIdx.y, tid = threadIdx.x;
    __shared__ float xb[768];
    __shared__ float vbuf[768];
    __shared__ float partS[NPOW];
    __shared__ float partT[NPOW];
    __shared__ double coefA[NCO];
    __shared__ double coefB[NCO];
    __shared__ float redf[1024];

    if (y == 2) {
        proj_256(sentence + b * 768, Ws, bs, final_ + b * 3840 + 2304, xb, redf, tid);
        return;
    }

    const bool scene = (y == 0);
    const float* kp = scene ? (scene_sent + b * 768) : (target + b * 768);
    for (int i = tid; i < 768; i += 256) xb[i] = kp[i];
    if (scene)
        for (int i = tid; i < 768; i += 256) vbuf[i] = scene_desc[b * 768 + i];
    __syncthreads();
    if (scene) scan768_ST(xb, vbuf, partS, partT, tid);
    else       scan768_S(xb, partS, tid);
    __syncthreads();

    if (tid < NCO) {
        double fact = 1.0;
        for (int i = 2; i <= tid; ++i) fact *= (double)i;
        const double inv = 1.0 / fact;
        coefA[tid] = (double)partS[tid] * inv;
        coefB[tid] = scene ? ((double)partT[tid] * inv)
                           : ((double)partS[tid + 1] * inv);
    }
    __syncthreads();

    double q[3], num[3], den[3];
    #pragma unroll
    for (int j = 0; j < 3; ++j) {
        const int r = tid + 256 * j;
        q[j] = 4.0 * (double)(scene ? xb[r] : other[b * 768 + r]);
        den[j] = coefA[NCO - 1];
        num[j] = coefB[NCO - 1];
    }
    for (int n = NCO - 2; n >= 0; --n) {
        const double a = coefA[n], cc = coefB[n];
        #pragma unroll
        for (int j = 0; j < 3; ++j) {
            den[j] = fma(den[j], q[j], a);
            num[j] = fma(num[j], q[j], cc);
        }
    }
    #pragma unroll
    for (int j = 0; j < 3; ++j) {
        const double ratio = scene ? (num[j] / den[j]) : (4.0 * num[j] / den[j]);
        ctx[b * 1536 + (scene ? 0 : 768) + tid + 256 * j] = (float)ratio;
    }
}

// K2: grid (32,11), 256 threads.  y=0..8 fused slices, y=9,10 ctx projections.
__global__ __launch_bounds__(256) void k2_fused_kernel(
    const float* __restrict__ sentence,
    const float* __restrict__ ctx,
    const float* __restrict__ Ws,
    const float* __restrict__ bs,
    float* __restrict__ final_)
{
    const int b = blockIdx.x, y = blockIdx.y, tid = threadIdx.x;
    __shared__ float fb[2304];
    __shared__ float redbuf[2][2048];
    __shared__ float partS[NPOW];
    __shared__ double coefA[NCO];
    __shared__ double coefB[NCO];
    __shared__ float redf[1024];

    if (y >= 9) {
        const int p = y - 8;     // 1 or 2
        proj_256(ctx + b * 1536 + (p - 1) * 768, Ws, bs,
                 final_ + b * 3840 + 2304 + p * 512, fb, redf, tid);
        return;
    }

    for (int i = tid; i < 2304; i += 256)
        fb[i] = (i < 768) ? sentence[b * 768 + i] : ctx[b * 1536 + (i - 768)];
    __syncthreads();

    float g[9], pw[9];
    #pragma unroll
    for (int j = 0; j < 9; ++j) { g[j] = fb[tid + 256 * j] * 0.25f; pw[j] = 1.f; }

    for (int c = 0; c < 10; ++c) {
        float* buf = redbuf[c & 1];
        #pragma unroll
        for (int m = 0; m < 8; ++m) {
            buf[m * 256 + tid] = (((pw[0] + pw[1]) + (pw[2] + pw[3]))
                                + ((pw[4] + pw[5]) + (pw[6] + pw[7]))) + pw[8];
            #pragma unroll
            for (int j = 0; j < 9; ++j) pw[j] *= g[j];
        }
        __syncthreads();
        const int n = tid >> 5, l = tid & 31;
        const float* src = buf + n * 256 + l;
        float acc = ((src[0] + src[32]) + (src[64] + src[96]))
                  + ((src[128] + src[160]) + (src[192] + src[224]));
        acc += __shfl_xor(acc, 1, 64);
        acc += __shfl_xor(acc, 2, 64);
        acc += __shfl_xor(acc, 4, 64);
        acc += __shfl_xor(acc, 8, 64);
        acc += __shfl_xor(acc, 16, 64);
        if (l == 0) partS[c * 8 + n] = acc;
    }
    __syncthreads();

    if (tid < NCO) {
        double fact = 1.0;
        for (int i = 2; i <= tid; ++i) fact *= (double)i;
        const double inv = 1.0 / fact;
        coefA[tid] = (double)partS[tid] * inv;
        coefB[tid] = (double)partS[tid + 1] * inv;
    }
    __syncthreads();

    const int r = y * 256 + tid;
    const double x = 4.0 * (double)fb[r];
    double den = coefA[NCO - 1], num = coefB[NCO - 1];
    for (int n = NCO - 2; n >= 0; --n) {
        den = fma(den, x, coefA[n]);
        num = fma(num, x, coefB[n]);
    }
    final_[b * 3840 + r] = (float)(4.0 * num / den);
}

// MLP stage 1, K-split across blocks: grid (32,8), 1024 threads.
__global__ __launch_bounds__(1024) void mlp_part_kernel(
    const float* __restrict__ final_,
    const float* __restrict__ W1,   // [3840, 256]
    float* __restrict__ hpart)      // [32][8][256]
{
    const int b = blockIdx.x;
    const int c = blockIdx.y;
    const int tid = threadIdx.x;
    const int base = c * 480;

    __shared__ float fb[480];
    __shared__ float red[16][256];
    if (tid < 480) fb[tid] = final_[b * 3840 + base + tid];
    __syncthreads();

    const int g = tid >> 6;         // wave id, 16 waves
    const int q = tid & 63;         // column quad
    const float4* __restrict__ Wv = (const float4*)W1;   // [3840][64]
    float ax = 0.f, ay = 0.f, az = 0.f, aw = 0.f;
    const int l0 = g * 30;
    #pragma unroll 5
    for (int kk = 0; kk < 30; ++kk) {
        const float xv = fb[l0 + kk];
        const float4 w = Wv[(base + l0 + kk) * 64 + q];
        ax += xv * w.x; ay += xv * w.y; az += xv * w.z; aw += xv * w.w;
    }
    red[g][q * 4 + 0] = ax;
    red[g][q * 4 + 1] = ay;
    red[g][q * 4 + 2] = az;
    red[g][q * 4 + 3] = aw;
    __syncthreads();

    if (tid < 256) {
        float s = 0.f;
        #pragma unroll
        for (int g2 = 0; g2 < 16; ++g2) s += red[g2][tid];
        hpart[(b * 8 + c) * 256 + tid] = s;
    }
}

// MLP tail: combine K-partials, relu, [256x7] head, sigmoid. grid 32, 512 threads.
__global__ __launch_bounds__(512) void mlp_tail_kernel(
    const float* __restrict__ hpart,
    const float* __restrict__ b1,
    const float* __restrict__ W2,   // [256, 7]
    const float* __restrict__ b2,
    float* __restrict__ out)        // [32, 7]
{
    const int b = blockIdx.x;
    const int tid = threadIdx.x;

    __shared__ float hb[256];
    if (tid < 256) {
        float s = b1[tid];
        #pragma unroll
        for (int c = 0; c < 8; ++c) s += hpart[(b * 8 + c) * 256 + tid];
        hb[tid] = fmaxf(s, 0.f);
    }
    __syncthreads();

    const int w = tid >> 6;
    const int lane = tid & 63;
    if (w < 7) {
        float a = 0.f;
        #pragma unroll
        for (int c = lane; c < 256; c += 64)
            a += hb[c] * W2[c * 7 + w];
        #pragma unroll
        for (int off = 32; off > 0; off >>= 1)
            a += __shfl_down(a, off, 64);
        if (lane == 0)
            out[b * 7 + w] = 1.f / (1.f + __expf(-(a + b2[w])));
    }
}

extern "C" void kernel_launch(void* const* d_in, const int* in_sizes, int n_in,
                              void* d_out, int out_size, void* d_ws, size_t ws_size,
                              hipStream_t stream) {
    const float* sentence   = (const float*)d_in[0];
    const float* target     = (const float*)d_in[1];
    const float* other      = (const float*)d_in[2];
    const float* scene_desc = (const float*)d_in[3];
    const float* scene_sent = (const float*)d_in[4];
    const float* Ws         = (const float*)d_in[5];
    const float* bs         = (const float*)d_in[6];
    const float* W1         = (const float*)d_in[7];
    const float* b1         = (const float*)d_in[8];
    const float* W2         = (const float*)d_in[9];
    const float* b2         = (const float*)d_in[10];
    float* out = (float*)d_out;

    float* ctx    = (float*)d_ws;             // 32*1536
    float* final_ = ctx + 32 * 1536;          // 32*3840
    float* hpart  = final_ + 32 * 3840;       // 32*8*256

    k1_small_kernel<<<dim3(32, 3), 256, 0, stream>>>(sentence, target, other,
                                                     scene_desc, scene_sent,
                                                     Ws, bs, ctx, final_);
    k2_fused_kernel<<<dim3(32, 11), 256, 0, stream>>>(sentence, ctx, Ws, bs, final_);
    mlp_part_kernel<<<dim3(32, 8), 1024, 0, stream>>>(final_, W1, hpart);
    mlp_tail_kernel<<<32, 512, 0, stream>>>(hpart, b1, W2, b2, out);
}